// Round 1
// baseline (823.227 us; speedup 1.0000x reference)
//
#include <hip/hip_runtime.h>
#include <hip/hip_bf16.h>

#define D 128

// ---------- helpers ----------
__device__ __forceinline__ float bf2f(unsigned short u) {
    union { unsigned int i; float f; } c; c.i = ((unsigned int)u) << 16; return c.f;
}
__device__ __forceinline__ unsigned short f2bf(float f) {
    union { float f; unsigned int i; } c; c.f = f;
    unsigned int x = c.i + 0x7fffu + ((c.i >> 16) & 1u);   // RNE
    return (unsigned short)(x >> 16);
}
__device__ __forceinline__ float eluf(float x) { return x > 0.f ? x : (expf(x) - 1.f); }

// ---------- prep: A' = W1_top - W1_bot ----------
__global__ __launch_bounds__(256) void k_prep(const float* __restrict__ W1,
                                              float* __restrict__ Ap) {
    int i = blockIdx.x * 256 + threadIdx.x;
    if (i < 128 * 128) Ap[i] = W1[i] - W1[128 * 128 + i];
}

// ---------- CSR build: histogram ----------
__global__ __launch_bounds__(256) void k_hist(const int* __restrict__ rdst,
                                              const int* __restrict__ rsrc,
                                              const int* __restrict__ pdst,
                                              int* __restrict__ counts,
                                              int e_r, int e_p, int n_item, int n_stu) {
    int i = blockIdx.x * 256 + threadIdx.x;
    int total = 2 * e_r + e_p;
    if (i >= total) return;
    if (i < e_r)            atomicAdd(&counts[rdst[i]], 1);
    else if (i < 2 * e_r)   atomicAdd(&counts[n_item + rsrc[i - e_r]], 1);
    else                    atomicAdd(&counts[n_item + n_stu + pdst[i - 2 * e_r]], 1);
}

// ---------- scan phase A: per-1024-tile sums ----------
__global__ __launch_bounds__(256) void k_scanA(const int* __restrict__ counts,
                                               int* __restrict__ bsums, int NN) {
    __shared__ int red[256];
    int tid = threadIdx.x;
    int base = blockIdx.x * 1024 + tid * 4;
    int s = 0;
    #pragma unroll
    for (int j = 0; j < 4; ++j) { int idx = base + j; if (idx < NN) s += counts[idx]; }
    red[tid] = s; __syncthreads();
    for (int off = 128; off; off >>= 1) {
        if (tid < off) red[tid] += red[tid + off];
        __syncthreads();
    }
    if (tid == 0) bsums[blockIdx.x] = red[0];
}

// ---------- scan phase B: exclusive scan of <=256 tile sums (1 block) ----------
__global__ __launch_bounds__(256) void k_scanB(int* __restrict__ bsums, int nb) {
    __shared__ int wsum[4];
    int tid = threadIdx.x;
    int lane = tid & 63, w = tid >> 6;
    int v = (tid < nb) ? bsums[tid] : 0;
    int orig = v;
    #pragma unroll
    for (int off = 1; off < 64; off <<= 1) {
        int t = __shfl_up(v, off, 64);
        if (lane >= off) v += t;
    }
    if (lane == 63) wsum[w] = v;
    __syncthreads();
    int wo = 0;
    #pragma unroll
    for (int i = 0; i < 4; ++i) if (i < w) wo += wsum[i];
    if (tid < nb) bsums[tid] = wo + v - orig;
}

// ---------- scan phase C: full exclusive scan -> rowptr & cursor ----------
__global__ __launch_bounds__(256) void k_scanC(const int* __restrict__ counts,
                                               const int* __restrict__ bsums,
                                               int* __restrict__ rowptr,
                                               int* __restrict__ cursor,
                                               int NN, int total) {
    __shared__ int wsum[4];
    int tid = threadIdx.x;
    int lane = tid & 63, w = tid >> 6;
    int base = blockIdx.x * 1024 + tid * 4;
    int c[4]; int ls = 0;
    #pragma unroll
    for (int j = 0; j < 4; ++j) { int idx = base + j; c[j] = (idx < NN) ? counts[idx] : 0; ls += c[j]; }
    int v = ls;
    #pragma unroll
    for (int off = 1; off < 64; off <<= 1) {
        int t = __shfl_up(v, off, 64);
        if (lane >= off) v += t;
    }
    if (lane == 63) wsum[w] = v;
    __syncthreads();
    int wo = 0;
    #pragma unroll
    for (int i = 0; i < 4; ++i) if (i < w) wo += wsum[i];
    int run = bsums[blockIdx.x] + wo + (v - ls);
    #pragma unroll
    for (int j = 0; j < 4; ++j) {
        int idx = base + j;
        if (idx < NN) { rowptr[idx] = run; cursor[idx] = run; if (idx == NN - 1) rowptr[NN] = total; }
        run += c[j];
    }
}

// ---------- scatter edge ids into CSR ----------
__global__ __launch_bounds__(256) void k_scatter(const int* __restrict__ rdst,
                                                 const int* __restrict__ rsrc,
                                                 const int* __restrict__ pdst,
                                                 int* __restrict__ cursor,
                                                 int* __restrict__ edgeid,
                                                 int e_r, int e_p, int n_item, int n_stu) {
    int i = blockIdx.x * 256 + threadIdx.x;
    int total = 2 * e_r + e_p;
    if (i >= total) return;
    int g, loc;
    if (i < e_r)          { g = rdst[i];                       loc = i; }
    else if (i < 2 * e_r) { g = n_item + rsrc[i - e_r];        loc = i - e_r; }
    else                  { g = n_item + n_stu + pdst[i - 2 * e_r]; loc = i - 2 * e_r; }
    int slot = atomicAdd(&cursor[g], 1);
    edgeid[slot] = loc;
}

// ---------- aggregation: one 32-lane half-wave per destination node ----------
__global__ __launch_bounds__(256) void k_agg(const float* __restrict__ xs,
                                             const float* __restrict__ xi,
                                             const unsigned short* __restrict__ U,
                                             const unsigned short* __restrict__ V,
                                             const int* __restrict__ rsrc,
                                             const int* __restrict__ rdst,
                                             const int* __restrict__ psrc,
                                             const int* __restrict__ rowptr,
                                             const int* __restrict__ edgeid,
                                             float* __restrict__ agg_item,
                                             float* __restrict__ agg_stu,
                                             float* __restrict__ hmean,
                                             int n_item, int n_stu) {
    int t = blockIdx.x * 256 + threadIdx.x;
    int node = t >> 5;
    int lane = t & 31;
    int NN = n_item + 2 * n_stu;
    if (node >= NN) return;
    int p0 = rowptr[node], p1 = rowptr[node + 1];
    int cnt = p1 - p0;
    float inv = 1.0f / (float)max(cnt, 1);
    float ax = 0.f, ay = 0.f, az = 0.f, aw = 0.f;
    if (node < n_item) {
        for (int p = p0; p < p1; ++p) {
            int e = edgeid[p];
            const float4 vv = *(const float4*)(xs + (size_t)rsrc[e] * D + lane * 4);
            ax += vv.x; ay += vv.y; az += vv.z; aw += vv.w;
        }
        float4 o = { ax * inv, ay * inv, az * inv, aw * inv };
        *(float4*)(agg_item + (size_t)node * D + lane * 4) = o;
    } else if (node < n_item + n_stu) {
        int n = node - n_item;
        for (int p = p0; p < p1; ++p) {
            int e = edgeid[p];
            const float4 vv = *(const float4*)(xi + (size_t)rdst[e] * D + lane * 4);
            ax += vv.x; ay += vv.y; az += vv.z; aw += vv.w;
        }
        float4 o = { ax * inv, ay * inv, az * inv, aw * inv };
        *(float4*)(agg_stu + (size_t)n * D + lane * 4) = o;
    } else {
        int n = node - n_item - n_stu;
        ushort4 vu = *(const ushort4*)(V + (size_t)n * D + lane * 4);
        float vx = bf2f(vu.x), vy = bf2f(vu.y), vz = bf2f(vu.z), vw = bf2f(vu.w);
        for (int p = p0; p < p1; ++p) {
            int e = edgeid[p];
            ushort4 uu = *(const ushort4*)(U + (size_t)psrc[e] * D + lane * 4);
            ax += eluf(bf2f(uu.x) + vx);
            ay += eluf(bf2f(uu.y) + vy);
            az += eluf(bf2f(uu.z) + vz);
            aw += eluf(bf2f(uu.w) + vw);
        }
        float4 o = { ax * inv, ay * inv, az * inv, aw * inv };
        *(float4*)(hmean + (size_t)n * D + lane * 4) = o;
    }
}

// ---------- fp32 GEMM: C[M,128] = sum_s X_s[M,128] @ W_s[128,128] (+bias [+gated b2]) ----------
// 64-row x 128-col tile / block of 256 threads; K staged in chunks of 32.
template<int NSRC, bool BF16OUT, bool DO_ELU, bool GATED>
__global__ __launch_bounds__(256) void k_gemm(const float* __restrict__ X0, const float* __restrict__ W0,
                                              const float* __restrict__ X1, const float* __restrict__ W1,
                                              const float* __restrict__ X2, const float* __restrict__ W2,
                                              const float* __restrict__ bias,
                                              const float* __restrict__ bias2,
                                              const int* __restrict__ gate,
                                              float scale, int M,
                                              float* __restrict__ Cf,
                                              unsigned short* __restrict__ Cb) {
    __shared__ float Xs[64][36];     // +4 pad: rows 144B apart -> conflict-free float4 reads
    __shared__ float Ws[32][128];
    const int tid = threadIdx.x;
    const int row0 = blockIdx.x * 64;
    const int tx = tid & 15, ty = tid >> 4;

    float acc[4][8];
    #pragma unroll
    for (int i = 0; i < 4; ++i)
        #pragma unroll
        for (int j = 0; j < 8; ++j) acc[i][j] = 0.f;

    for (int s = 0; s < NSRC; ++s) {
        const float* Xp = (s == 0) ? X0 : ((s == 1) ? X1 : X2);
        const float* Wp = (s == 0) ? W0 : ((s == 1) ? W1 : W2);
        for (int kc = 0; kc < 4; ++kc) {
            __syncthreads();
            {   // stage X tile: 64 rows x 32 cols
                int r = tid >> 2, cg = tid & 3;
                int gr = row0 + r; if (gr >= M) gr = M - 1;
                const float* src = Xp + (size_t)gr * D + kc * 32 + cg * 8;
                float4 a = ((const float4*)src)[0];
                float4 b = ((const float4*)src)[1];
                *(float4*)&Xs[r][cg * 8]     = a;
                *(float4*)&Xs[r][cg * 8 + 4] = b;
            }
            {   // stage W tile: 32 k-rows x 128 cols
                int r = tid >> 3, cg = tid & 7;
                const float* src = Wp + (size_t)(kc * 32 + r) * D + cg * 16;
                float4 a0 = ((const float4*)src)[0];
                float4 a1 = ((const float4*)src)[1];
                float4 a2 = ((const float4*)src)[2];
                float4 a3 = ((const float4*)src)[3];
                *(float4*)&Ws[r][cg * 16]      = a0;
                *(float4*)&Ws[r][cg * 16 + 4]  = a1;
                *(float4*)&Ws[r][cg * 16 + 8]  = a2;
                *(float4*)&Ws[r][cg * 16 + 12] = a3;
            }
            __syncthreads();
            #pragma unroll
            for (int k4 = 0; k4 < 8; ++k4) {
                float4 xv[4];
                #pragma unroll
                for (int i = 0; i < 4; ++i) xv[i] = *(float4*)&Xs[ty + 16 * i][k4 * 4];
                #pragma unroll
                for (int j = 0; j < 4; ++j) {
                    int k = k4 * 4 + j;
                    float4 w0 = *(float4*)&Ws[k][tx * 8];
                    float4 w1 = *(float4*)&Ws[k][tx * 8 + 4];
                    #pragma unroll
                    for (int i = 0; i < 4; ++i) {
                        float xk = ((const float*)&xv[i])[j];
                        acc[i][0] += xk * w0.x; acc[i][1] += xk * w0.y;
                        acc[i][2] += xk * w0.z; acc[i][3] += xk * w0.w;
                        acc[i][4] += xk * w1.x; acc[i][5] += xk * w1.y;
                        acc[i][6] += xk * w1.z; acc[i][7] += xk * w1.w;
                    }
                }
            }
        }
    }

    // epilogue
    const int c0 = tx * 8;
    float bv[8], b2v[8];
    #pragma unroll
    for (int j = 0; j < 8; ++j) {
        bv[j]  = bias  ? bias[c0 + j]  : 0.f;
        b2v[j] = GATED ? bias2[c0 + j] : 0.f;
    }
    #pragma unroll
    for (int i = 0; i < 4; ++i) {
        int r = row0 + ty + 16 * i;
        if (r >= M) continue;
        float g = 1.f;
        if (GATED) g = (gate[r] > 0) ? 1.f : 0.f;
        float o[8];
        #pragma unroll
        for (int j = 0; j < 8; ++j) {
            float v = acc[i][j] + bv[j];
            if (GATED) v += g * b2v[j];
            v *= scale;
            if (DO_ELU) v = eluf(v);
            o[j] = v;
        }
        if (BF16OUT) {
            ushort4 u0 = { f2bf(o[0]), f2bf(o[1]), f2bf(o[2]), f2bf(o[3]) };
            ushort4 u1 = { f2bf(o[4]), f2bf(o[5]), f2bf(o[6]), f2bf(o[7]) };
            *(ushort4*)(Cb + (size_t)r * D + c0)     = u0;
            *(ushort4*)(Cb + (size_t)r * D + c0 + 4) = u1;
        } else {
            float4 f0 = { o[0], o[1], o[2], o[3] };
            float4 f1 = { o[4], o[5], o[6], o[7] };
            *(float4*)(Cf + (size_t)r * D + c0)     = f0;
            *(float4*)(Cf + (size_t)r * D + c0 + 4) = f1;
        }
    }
}

// ---------- BatchNorm stats (per-column sum & sumsq) ----------
__global__ __launch_bounds__(256) void k_bnstats(const float* __restrict__ X, int M,
                                                 float* __restrict__ stats) {
    int c = threadIdx.x & 127;
    int half = threadIdx.x >> 7;
    int r0 = blockIdx.x * 256;
    int rend = min(r0 + 256, M);
    float s = 0.f, q = 0.f;
    for (int r = r0 + half; r < rend; r += 2) {
        float v = X[(size_t)r * D + c];
        s += v; q += v * v;
    }
    atomicAdd(&stats[c], s);
    atomicAdd(&stats[128 + c], q);
}

// ---------- BatchNorm apply (in place) ----------
__global__ __launch_bounds__(256) void k_bnapply(float* __restrict__ X, int M,
                                                 const float* __restrict__ stats,
                                                 const float* __restrict__ gamma,
                                                 const float* __restrict__ beta) {
    int i = blockIdx.x * 256 + threadIdx.x;
    if (i >= M * D) return;
    int c = i & 127;
    float mu = stats[c] / (float)M;
    float var = stats[128 + c] / (float)M - mu * mu;
    float inv = rsqrtf(var + 1e-5f);
    X[i] = gamma[c] * (X[i] - mu) * inv + beta[c];
}

// ---------- host ----------
extern "C" void kernel_launch(void* const* d_in, const int* in_sizes, int n_in,
                              void* d_out, int out_size, void* d_ws, size_t ws_size,
                              hipStream_t stream) {
    const float* x_stu   = (const float*)d_in[0];
    const float* x_item  = (const float*)d_in[1];
    const int*   rsrc    = (const int*)d_in[2];
    const int*   rdst    = (const int*)d_in[3];
    const int*   psrc    = (const int*)d_in[4];
    const int*   pdst    = (const int*)d_in[5];
    const float* it_Wl   = (const float*)d_in[6];
    const float* it_Wr   = (const float*)d_in[7];
    const float* it_b    = (const float*)d_in[8];
    const float* st_Wl   = (const float*)d_in[9];
    const float* st_Wr   = (const float*)d_in[10];
    const float* st_b    = (const float*)d_in[11];
    const float* sc_W1   = (const float*)d_in[12];
    const float* sc_b1   = (const float*)d_in[13];
    const float* sc_W2   = (const float*)d_in[14];
    const float* sc_b2   = (const float*)d_in[15];
    const float* bn_it_g = (const float*)d_in[16];
    const float* bn_it_b = (const float*)d_in[17];
    const float* bn_st_g = (const float*)d_in[18];
    const float* bn_st_b = (const float*)d_in[19];

    const int n_stu  = in_sizes[0] / D;
    const int n_item = in_sizes[1] / D;
    const int e_r    = in_sizes[2];
    const int e_p    = in_sizes[4];
    const int NN     = n_item + 2 * n_stu;
    const int tot_e  = 2 * e_r + e_p;
    const int nb     = (NN + 1023) / 1024;

    // workspace layout
    char* w = (char*)d_ws;
    size_t off = 0;
    auto alloc = [&](size_t bytes) { char* p = w + off; off = (off + bytes + 255) & ~(size_t)255; return p; };
    unsigned short* U      = (unsigned short*)alloc((size_t)n_stu * D * 2);
    unsigned short* V      = (unsigned short*)alloc((size_t)n_stu * D * 2);
    float*          hmean  = (float*)alloc((size_t)n_stu * D * 4);
    float*          Aprime = (float*)alloc(128 * 128 * 4);
    int*            counts = (int*)alloc((size_t)NN * 4);
    int*            rowptr = (int*)alloc((size_t)(NN + 1) * 4);
    int*            cursor = (int*)alloc((size_t)NN * 4);
    int*            bsums  = (int*)alloc(256 * 4);
    int*            edgeid = (int*)alloc((size_t)tot_e * 4);
    float*          stats  = (float*)alloc(512 * 4);
    (void)ws_size; (void)n_in; (void)out_size;

    // agg_item / agg_stu staged directly in d_out (row-disjoint read->write in GEMM)
    float* out_item = (float*)d_out;                       // [n_item,128]
    float* out_stu  = (float*)d_out + (size_t)n_item * D;  // [n_stu,128]
    float* agg_item = out_item;
    float* agg_stu  = out_stu;

    hipMemsetAsync(counts, 0, (size_t)NN * 4, stream);
    hipMemsetAsync(stats, 0, 512 * 4, stream);

    k_prep<<<(128 * 128 + 255) / 256, 256, 0, stream>>>(sc_W1, Aprime);
    k_hist<<<(tot_e + 255) / 256, 256, 0, stream>>>(rdst, rsrc, pdst, counts, e_r, e_p, n_item, n_stu);
    k_scanA<<<nb, 256, 0, stream>>>(counts, bsums, NN);
    k_scanB<<<1, 256, 0, stream>>>(bsums, nb);
    k_scanC<<<nb, 256, 0, stream>>>(counts, bsums, rowptr, cursor, NN, tot_e);
    k_scatter<<<(tot_e + 255) / 256, 256, 0, stream>>>(rdst, rsrc, pdst, cursor, edgeid, e_r, e_p, n_item, n_stu);

    // U = x_stu @ A' + b1 ; V = x_stu @ W1_bot   (bf16 out)
    int gs = (n_stu + 63) / 64;
    k_gemm<1, true, false, false><<<gs, 256, 0, stream>>>(
        x_stu, Aprime, nullptr, nullptr, nullptr, nullptr,
        sc_b1, nullptr, nullptr, 1.f, n_stu, nullptr, U);
    k_gemm<1, true, false, false><<<gs, 256, 0, stream>>>(
        x_stu, sc_W1 + 128 * 128, nullptr, nullptr, nullptr, nullptr,
        nullptr, nullptr, nullptr, 1.f, n_stu, nullptr, V);

    k_agg<<<((size_t)NN * 32 + 255) / 256, 256, 0, stream>>>(
        x_stu, x_item, U, V, rsrc, rdst, psrc, rowptr, edgeid,
        agg_item, agg_stu, hmean, n_item, n_stu);

    // item_pre = elu(agg_item@Wl + x_item@Wr + b)
    k_gemm<2, false, true, false><<<(n_item + 63) / 64, 256, 0, stream>>>(
        agg_item, it_Wl, x_item, it_Wr, nullptr, nullptr,
        it_b, nullptr, nullptr, 1.f, n_item, out_item, nullptr);

    // stu_pre = elu(0.5*(agg_stu@Wl + x_stu@Wr + b_st + hmean@W2 + [deg>0]*b2))
    k_gemm<3, false, true, true><<<gs, 256, 0, stream>>>(
        agg_stu, st_Wl, x_stu, st_Wr, hmean, sc_W2,
        st_b, sc_b2, counts + n_item + n_stu, 0.5f, n_stu, out_stu, nullptr);

    // BatchNorm (training-mode, biased var)
    k_bnstats<<<(n_item + 255) / 256, 256, 0, stream>>>(out_item, n_item, stats);
    k_bnstats<<<(n_stu + 255) / 256, 256, 0, stream>>>(out_stu, n_stu, stats + 256);
    k_bnapply<<<((size_t)n_item * D + 255) / 256, 256, 0, stream>>>(out_item, n_item, stats, bn_it_g, bn_it_b);
    k_bnapply<<<((size_t)n_stu * D + 255) / 256, 256, 0, stream>>>(out_stu, n_stu, stats + 256, bn_st_g, bn_st_b);
}

// Round 2
// 657.772 us; speedup vs baseline: 1.2515x; 1.2515x over previous
//
#include <hip/hip_runtime.h>
#include <hip/hip_bf16.h>

#define D 128

typedef unsigned short ushort_t;
typedef __attribute__((ext_vector_type(8))) short bf16x8;
typedef __attribute__((ext_vector_type(4))) float f32x4;

// ---------- helpers ----------
__device__ __forceinline__ float bf2f(unsigned short u) {
    union { unsigned int i; float f; } c; c.i = ((unsigned int)u) << 16; return c.f;
}
__device__ __forceinline__ unsigned short f2bf(float f) {
    union { float f; unsigned int i; } c; c.f = f;
    unsigned int x = c.i + 0x7fffu + ((c.i >> 16) & 1u);   // RNE
    return (unsigned short)(x >> 16);
}
__device__ __forceinline__ float eluf(float x) { return x > 0.f ? x : (expf(x) - 1.f); }

// async global->LDS, 16B per lane; LDS dest = wave-uniform base + lane*16
__device__ __forceinline__ void gload_lds16(const void* g, void* l) {
    __builtin_amdgcn_global_load_lds(
        (const __attribute__((address_space(1))) unsigned int*)g,
        (__attribute__((address_space(3))) unsigned int*)l, 16, 0, 0);
}

// ---------- weight pack: 7 sources of [128x128] fp32 -> fragment-ordered bf16 ----------
// Per source: [kc(4)][nt(8)][lane(64)][j(8)] ; element = W[k][n], k=kc*32+(lane>>4)*8+j, n=nt*16+(lane&15)
// s=0: A' = W1_top - W1_bot ; s=1: W1_bot ; s=2: it_Wl ; s=3: it_Wr ; s=4: st_Wl ; s=5: st_Wr ; s=6: sc_W2
__global__ __launch_bounds__(256) void k_pack(const float* __restrict__ sc_W1,
                                              const float* __restrict__ it_Wl,
                                              const float* __restrict__ it_Wr,
                                              const float* __restrict__ st_Wl,
                                              const float* __restrict__ st_Wr,
                                              const float* __restrict__ sc_W2,
                                              ushort_t* __restrict__ Bpack) {
    int tid = blockIdx.x * 256 + threadIdx.x;
    if (tid >= 7 * 16384) return;
    int s = tid >> 14;
    int r = tid & 16383;
    int j = r & 7;
    int lane = (r >> 3) & 63;
    int tile = r >> 9;              // 0..31
    int nt = tile & 7, kc = tile >> 3;
    int n = nt * 16 + (lane & 15);
    int k = kc * 32 + ((lane >> 4) << 3) + j;
    float v;
    switch (s) {
        case 0: v = sc_W1[k * 128 + n] - sc_W1[(128 + k) * 128 + n]; break;
        case 1: v = sc_W1[(128 + k) * 128 + n]; break;
        case 2: v = it_Wl[k * 128 + n]; break;
        case 3: v = it_Wr[k * 128 + n]; break;
        case 4: v = st_Wl[k * 128 + n]; break;
        case 5: v = st_Wr[k * 128 + n]; break;
        default: v = sc_W2[k * 128 + n]; break;
    }
    Bpack[tid] = f2bf(v);
}

// ---------- CSR build: histogram ----------
__global__ __launch_bounds__(256) void k_hist(const int* __restrict__ rdst,
                                              const int* __restrict__ rsrc,
                                              const int* __restrict__ pdst,
                                              int* __restrict__ counts,
                                              int e_r, int e_p, int n_item, int n_stu) {
    int i = blockIdx.x * 256 + threadIdx.x;
    int total = 2 * e_r + e_p;
    if (i >= total) return;
    if (i < e_r)            atomicAdd(&counts[rdst[i]], 1);
    else if (i < 2 * e_r)   atomicAdd(&counts[n_item + rsrc[i - e_r]], 1);
    else                    atomicAdd(&counts[n_item + n_stu + pdst[i - 2 * e_r]], 1);
}

// ---------- scan phase A ----------
__global__ __launch_bounds__(256) void k_scanA(const int* __restrict__ counts,
                                               int* __restrict__ bsums, int NN) {
    __shared__ int red[256];
    int tid = threadIdx.x;
    int base = blockIdx.x * 1024 + tid * 4;
    int s = 0;
    #pragma unroll
    for (int j = 0; j < 4; ++j) { int idx = base + j; if (idx < NN) s += counts[idx]; }
    red[tid] = s; __syncthreads();
    for (int off = 128; off; off >>= 1) {
        if (tid < off) red[tid] += red[tid + off];
        __syncthreads();
    }
    if (tid == 0) bsums[blockIdx.x] = red[0];
}

// ---------- scan phase B ----------
__global__ __launch_bounds__(256) void k_scanB(int* __restrict__ bsums, int nb) {
    __shared__ int wsum[4];
    int tid = threadIdx.x;
    int lane = tid & 63, w = tid >> 6;
    int v = (tid < nb) ? bsums[tid] : 0;
    int orig = v;
    #pragma unroll
    for (int off = 1; off < 64; off <<= 1) {
        int t = __shfl_up(v, off, 64);
        if (lane >= off) v += t;
    }
    if (lane == 63) wsum[w] = v;
    __syncthreads();
    int wo = 0;
    #pragma unroll
    for (int i = 0; i < 4; ++i) if (i < w) wo += wsum[i];
    if (tid < nb) bsums[tid] = wo + v - orig;
}

// ---------- scan phase C ----------
__global__ __launch_bounds__(256) void k_scanC(const int* __restrict__ counts,
                                               const int* __restrict__ bsums,
                                               int* __restrict__ rowptr,
                                               int* __restrict__ cursor,
                                               int NN, int total) {
    __shared__ int wsum[4];
    int tid = threadIdx.x;
    int lane = tid & 63, w = tid >> 6;
    int base = blockIdx.x * 1024 + tid * 4;
    int c[4]; int ls = 0;
    #pragma unroll
    for (int j = 0; j < 4; ++j) { int idx = base + j; c[j] = (idx < NN) ? counts[idx] : 0; ls += c[j]; }
    int v = ls;
    #pragma unroll
    for (int off = 1; off < 64; off <<= 1) {
        int t = __shfl_up(v, off, 64);
        if (lane >= off) v += t;
    }
    if (lane == 63) wsum[w] = v;
    __syncthreads();
    int wo = 0;
    #pragma unroll
    for (int i = 0; i < 4; ++i) if (i < w) wo += wsum[i];
    int run = bsums[blockIdx.x] + wo + (v - ls);
    #pragma unroll
    for (int j = 0; j < 4; ++j) {
        int idx = base + j;
        if (idx < NN) { rowptr[idx] = run; cursor[idx] = run; if (idx == NN - 1) rowptr[NN] = total; }
        run += c[j];
    }
}

// ---------- scatter edge ids into CSR ----------
__global__ __launch_bounds__(256) void k_scatter(const int* __restrict__ rdst,
                                                 const int* __restrict__ rsrc,
                                                 const int* __restrict__ pdst,
                                                 int* __restrict__ cursor,
                                                 int* __restrict__ edgeid,
                                                 int e_r, int e_p, int n_item, int n_stu) {
    int i = blockIdx.x * 256 + threadIdx.x;
    int total = 2 * e_r + e_p;
    if (i >= total) return;
    int g, loc;
    if (i < e_r)          { g = rdst[i];                       loc = i; }
    else if (i < 2 * e_r) { g = n_item + rsrc[i - e_r];        loc = i - e_r; }
    else                  { g = n_item + n_stu + pdst[i - 2 * e_r]; loc = i - 2 * e_r; }
    int slot = atomicAdd(&cursor[g], 1);
    edgeid[slot] = loc;
}

// ---------- aggregation: one 32-lane half-wave per destination node ----------
__global__ __launch_bounds__(256) void k_agg(const float* __restrict__ xs,
                                             const float* __restrict__ xi,
                                             const unsigned short* __restrict__ U,
                                             const unsigned short* __restrict__ V,
                                             const int* __restrict__ rsrc,
                                             const int* __restrict__ rdst,
                                             const int* __restrict__ psrc,
                                             const int* __restrict__ rowptr,
                                             const int* __restrict__ edgeid,
                                             float* __restrict__ agg_item,
                                             float* __restrict__ agg_stu,
                                             float* __restrict__ hmean,
                                             int n_item, int n_stu) {
    int t = blockIdx.x * 256 + threadIdx.x;
    int node = t >> 5;
    int lane = t & 31;
    int NN = n_item + 2 * n_stu;
    if (node >= NN) return;
    int p0 = rowptr[node], p1 = rowptr[node + 1];
    int cnt = p1 - p0;
    float inv = 1.0f / (float)max(cnt, 1);
    float ax = 0.f, ay = 0.f, az = 0.f, aw = 0.f;
    if (node < n_item) {
        for (int p = p0; p < p1; ++p) {
            int e = edgeid[p];
            const float4 vv = *(const float4*)(xs + (size_t)rsrc[e] * D + lane * 4);
            ax += vv.x; ay += vv.y; az += vv.z; aw += vv.w;
        }
        float4 o = { ax * inv, ay * inv, az * inv, aw * inv };
        *(float4*)(agg_item + (size_t)node * D + lane * 4) = o;
    } else if (node < n_item + n_stu) {
        int n = node - n_item;
        for (int p = p0; p < p1; ++p) {
            int e = edgeid[p];
            const float4 vv = *(const float4*)(xi + (size_t)rdst[e] * D + lane * 4);
            ax += vv.x; ay += vv.y; az += vv.z; aw += vv.w;
        }
        float4 o = { ax * inv, ay * inv, az * inv, aw * inv };
        *(float4*)(agg_stu + (size_t)n * D + lane * 4) = o;
    } else {
        int n = node - n_item - n_stu;
        ushort4 vu = *(const ushort4*)(V + (size_t)n * D + lane * 4);
        float vx = bf2f(vu.x), vy = bf2f(vu.y), vz = bf2f(vu.z), vw = bf2f(vu.w);
        for (int p = p0; p < p1; ++p) {
            int e = edgeid[p];
            ushort4 uu = *(const ushort4*)(U + (size_t)psrc[e] * D + lane * 4);
            ax += eluf(bf2f(uu.x) + vx);
            ay += eluf(bf2f(uu.y) + vy);
            az += eluf(bf2f(uu.z) + vz);
            aw += eluf(bf2f(uu.w) + vw);
        }
        float4 o = { ax * inv, ay * inv, az * inv, aw * inv };
        *(float4*)(hmean + (size_t)n * D + lane * 4) = o;
    }
}

// ---------- MFMA GEMM: C[M,128] = sum_s X_s[M,128](fp32) @ W_s[128,128](packed bf16) ----------
// Block: 256 thr = 4 waves, tile 128 rows x 128 cols. Wave w: m-half w>>1, n-half w&1,
// computes 64x64 as 4x4 grid of 16x16x32 MFMAs. A converted fp32->bf16 during LDS staging.
// LDS fragment-ordered: tile = [kc][t8][lane][8 bf16], so frag reads are lane-contiguous b128.
template<int NSRC, bool BF16OUT, bool DO_ELU, bool GATED>
__global__ __launch_bounds__(256) void k_gemm(const float* __restrict__ X0,
                                              const float* __restrict__ X1,
                                              const float* __restrict__ X2,
                                              const ushort_t* __restrict__ Bpack,
                                              const float* __restrict__ bias,
                                              const float* __restrict__ bias2,
                                              const int* __restrict__ gate,
                                              float scale, int M,
                                              float* __restrict__ Cf,
                                              ushort_t* __restrict__ Cb) {
    __shared__ short As[8192];   // 16KB: [kc(2)][mt(8)][lane(64)][8]
    __shared__ short Bs[8192];   // 16KB: [kc(2)][nt(8)][lane(64)][8]
    const int tid = threadIdx.x;
    const int wave = tid >> 6;
    const int lane = tid & 63;
    const int mh = wave >> 1;            // m half (0/1)
    const int nh = wave & 1;             // n half (0/1)
    const int row0 = blockIdx.x * 128;
    const int q = lane >> 4;             // quad
    const int l15 = lane & 15;

    f32x4 acc[4][4];
    #pragma unroll
    for (int i = 0; i < 4; ++i)
        #pragma unroll
        for (int j = 0; j < 4; ++j) acc[i][j] = (f32x4){0.f, 0.f, 0.f, 0.f};

    for (int s = 0; s < NSRC; ++s) {
        const float* Xp = (s == 0) ? X0 : ((s == 1) ? X1 : X2);
        const ushort_t* Bp = Bpack + s * 16384;
        for (int h = 0; h < 2; ++h) {
            __syncthreads();
            // ---- stage A: 16 tiles (8 mt x 2 kc), 4 per wave; fp32->bf16 convert ----
            #pragma unroll
            for (int it = 0; it < 4; ++it) {
                int tile = wave * 4 + it;          // 0..15
                int mt = tile & 7, kc = tile >> 3;
                int row = row0 + mt * 16 + l15;
                if (row >= M) row = M - 1;
                int k = h * 64 + kc * 32 + (q << 3);
                const float* g = Xp + (size_t)row * D + k;
                float4 a0 = ((const float4*)g)[0];
                float4 a1 = ((const float4*)g)[1];
                short8_t:;
                short* dst = &As[tile * 512 + lane * 8];
                ushort4 u0 = { f2bf(a0.x), f2bf(a0.y), f2bf(a0.z), f2bf(a0.w) };
                ushort4 u1 = { f2bf(a1.x), f2bf(a1.y), f2bf(a1.z), f2bf(a1.w) };
                *(ushort4*)dst       = u0;
                *(ushort4*)(dst + 4) = u1;
            }
            // ---- stage B: 16 tiles, 4 per wave, async 16B/lane ----
            const ushort_t* bsrc = Bp + h * 8192;
            #pragma unroll
            for (int it = 0; it < 4; ++it) {
                int tile = wave * 4 + it;
                gload_lds16(bsrc + tile * 512 + lane * 8, &Bs[tile * 512]);
            }
            __syncthreads();
            // ---- compute: 2 k-chunks x 16 MFMAs ----
            #pragma unroll
            for (int kc = 0; kc < 2; ++kc) {
                bf16x8 a[4], b[4];
                #pragma unroll
                for (int i = 0; i < 4; ++i)
                    a[i] = *(bf16x8*)&As[(kc * 8 + mh * 4 + i) * 512 + lane * 8];
                #pragma unroll
                for (int j = 0; j < 4; ++j)
                    b[j] = *(bf16x8*)&Bs[(kc * 8 + nh * 4 + j) * 512 + lane * 8];
                #pragma unroll
                for (int i = 0; i < 4; ++i)
                    #pragma unroll
                    for (int j = 0; j < 4; ++j)
                        acc[i][j] = __builtin_amdgcn_mfma_f32_16x16x32_bf16(a[i], b[j], acc[i][j], 0, 0, 0);
            }
        }
    }

    // ---- epilogue ----
    float bv[4], b2v[4];
    #pragma unroll
    for (int j = 0; j < 4; ++j) {
        int col = (nh * 4 + j) * 16 + l15;
        bv[j]  = bias  ? bias[col]  : 0.f;
        b2v[j] = GATED ? bias2[col] : 0.f;
    }
    #pragma unroll
    for (int i = 0; i < 4; ++i) {
        int rowbase = row0 + (mh * 4 + i) * 16 + (q << 2);
        #pragma unroll
        for (int r = 0; r < 4; ++r) {
            int row = rowbase + r;
            if (row >= M) continue;
            float g = 1.f;
            if (GATED) g = (gate[row] > 0) ? 1.f : 0.f;
            #pragma unroll
            for (int j = 0; j < 4; ++j) {
                int col = (nh * 4 + j) * 16 + l15;
                float v = acc[i][j][r] + bv[j];
                if (GATED) v += g * b2v[j];
                v *= scale;
                if (DO_ELU) v = eluf(v);
                if (BF16OUT) Cb[(size_t)row * D + col] = f2bf(v);
                else         Cf[(size_t)row * D + col] = v;
            }
        }
    }
}

// ---------- BatchNorm stats ----------
__global__ __launch_bounds__(256) void k_bnstats(const float* __restrict__ X, int M,
                                                 float* __restrict__ stats) {
    int c = threadIdx.x & 127;
    int half = threadIdx.x >> 7;
    int r0 = blockIdx.x * 256;
    int rend = min(r0 + 256, M);
    float s = 0.f, q = 0.f;
    for (int r = r0 + half; r < rend; r += 2) {
        float v = X[(size_t)r * D + c];
        s += v; q += v * v;
    }
    atomicAdd(&stats[c], s);
    atomicAdd(&stats[128 + c], q);
}

// ---------- BatchNorm apply ----------
__global__ __launch_bounds__(256) void k_bnapply(float* __restrict__ X, int M,
                                                 const float* __restrict__ stats,
                                                 const float* __restrict__ gamma,
                                                 const float* __restrict__ beta) {
    int i = blockIdx.x * 256 + threadIdx.x;
    if (i >= M * D) return;
    int c = i & 127;
    float mu = stats[c] / (float)M;
    float var = stats[128 + c] / (float)M - mu * mu;
    float inv = rsqrtf(var + 1e-5f);
    X[i] = gamma[c] * (X[i] - mu) * inv + beta[c];
}

// ---------- host ----------
extern "C" void kernel_launch(void* const* d_in, const int* in_sizes, int n_in,
                              void* d_out, int out_size, void* d_ws, size_t ws_size,
                              hipStream_t stream) {
    const float* x_stu   = (const float*)d_in[0];
    const float* x_item  = (const float*)d_in[1];
    const int*   rsrc    = (const int*)d_in[2];
    const int*   rdst    = (const int*)d_in[3];
    const int*   psrc    = (const int*)d_in[4];
    const int*   pdst    = (const int*)d_in[5];
    const float* it_Wl   = (const float*)d_in[6];
    const float* it_Wr   = (const float*)d_in[7];
    const float* it_b    = (const float*)d_in[8];
    const float* st_Wl   = (const float*)d_in[9];
    const float* st_Wr   = (const float*)d_in[10];
    const float* st_b    = (const float*)d_in[11];
    const float* sc_W1   = (const float*)d_in[12];
    const float* sc_b1   = (const float*)d_in[13];
    const float* sc_W2   = (const float*)d_in[14];
    const float* sc_b2   = (const float*)d_in[15];
    const float* bn_it_g = (const float*)d_in[16];
    const float* bn_it_b = (const float*)d_in[17];
    const float* bn_st_g = (const float*)d_in[18];
    const float* bn_st_b = (const float*)d_in[19];

    const int n_stu  = in_sizes[0] / D;
    const int n_item = in_sizes[1] / D;
    const int e_r    = in_sizes[2];
    const int e_p    = in_sizes[4];
    const int NN     = n_item + 2 * n_stu;
    const int tot_e  = 2 * e_r + e_p;
    const int nb     = (NN + 1023) / 1024;

    // workspace layout
    char* w = (char*)d_ws;
    size_t off = 0;
    auto alloc = [&](size_t bytes) { char* p = w + off; off = (off + bytes + 255) & ~(size_t)255; return p; };
    ushort_t* U      = (ushort_t*)alloc((size_t)n_stu * D * 2);
    ushort_t* V      = (ushort_t*)alloc((size_t)n_stu * D * 2);
    float*    hmean  = (float*)alloc((size_t)n_stu * D * 4);
    ushort_t* Bpack  = (ushort_t*)alloc(7 * 16384 * 2);
    int*      counts = (int*)alloc((size_t)NN * 4);
    int*      rowptr = (int*)alloc((size_t)(NN + 1) * 4);
    int*      cursor = (int*)alloc((size_t)NN * 4);
    int*      bsums  = (int*)alloc(256 * 4);
    int*      edgeid = (int*)alloc((size_t)tot_e * 4);
    float*    stats  = (float*)alloc(512 * 4);
    (void)ws_size; (void)n_in; (void)out_size;

    // agg staged directly in d_out (row-disjoint read->write in final GEMMs)
    float* out_item = (float*)d_out;
    float* out_stu  = (float*)d_out + (size_t)n_item * D;
    float* agg_item = out_item;
    float* agg_stu  = out_stu;

    hipMemsetAsync(counts, 0, (size_t)NN * 4, stream);
    hipMemsetAsync(stats, 0, 512 * 4, stream);

    k_pack<<<(7 * 16384 + 255) / 256, 256, 0, stream>>>(sc_W1, it_Wl, it_Wr, st_Wl, st_Wr, sc_W2, Bpack);
    k_hist<<<(tot_e + 255) / 256, 256, 0, stream>>>(rdst, rsrc, pdst, counts, e_r, e_p, n_item, n_stu);
    k_scanA<<<nb, 256, 0, stream>>>(counts, bsums, NN);
    k_scanB<<<1, 256, 0, stream>>>(bsums, nb);
    k_scanC<<<nb, 256, 0, stream>>>(counts, bsums, rowptr, cursor, NN, tot_e);
    k_scatter<<<(tot_e + 255) / 256, 256, 0, stream>>>(rdst, rsrc, pdst, cursor, edgeid, e_r, e_p, n_item, n_stu);

    const int gs_stu  = (n_stu + 127) / 128;
    const int gs_item = (n_item + 127) / 128;

    // U = x_stu @ A' + b1 ; V = x_stu @ W1_bot   (bf16 out)
    k_gemm<1, true, false, false><<<gs_stu, 256, 0, stream>>>(
        x_stu, nullptr, nullptr, Bpack + 0 * 16384, sc_b1, nullptr, nullptr, 1.f, n_stu, nullptr, U);
    k_gemm<1, true, false, false><<<gs_stu, 256, 0, stream>>>(
        x_stu, nullptr, nullptr, Bpack + 1 * 16384, nullptr, nullptr, nullptr, 1.f, n_stu, nullptr, V);

    k_agg<<<((size_t)NN * 32 + 255) / 256, 256, 0, stream>>>(
        x_stu, x_item, U, V, rsrc, rdst, psrc, rowptr, edgeid,
        agg_item, agg_stu, hmean, n_item, n_stu);

    // item_pre = elu(agg_item@Wl + x_item@Wr + b)
    k_gemm<2, false, true, false><<<gs_item, 256, 0, stream>>>(
        agg_item, x_item, nullptr, Bpack + 2 * 16384, it_b, nullptr, nullptr, 1.f, n_item, out_item, nullptr);

    // stu_pre = elu(0.5*(agg_stu@Wl + x_stu@Wr + b_st + hmean@W2 + [deg>0]*b2))
    k_gemm<3, false, true, true><<<gs_stu, 256, 0, stream>>>(
        agg_stu, x_stu, hmean, Bpack + 4 * 16384, st_b, sc_b2, counts + n_item + n_stu, 0.5f, n_stu, out_stu, nullptr);

    // BatchNorm (training-mode, biased var)
    k_bnstats<<<(n_item + 255) / 256, 256, 0, stream>>>(out_item, n_item, stats);
    k_bnstats<<<(n_stu + 255) / 256, 256, 0, stream>>>(out_stu, n_stu, stats + 256);
    k_bnapply<<<((size_t)n_item * D + 255) / 256, 256, 0, stream>>>(out_item, n_item, stats, bn_it_g, bn_it_b);
    k_bnapply<<<((size_t)n_stu * D + 255) / 256, 256, 0, stream>>>(out_stu, n_stu, stats + 256, bn_st_g, bn_st_b);
}

// Round 3
// 483.793 us; speedup vs baseline: 1.7016x; 1.3596x over previous
//
#include <hip/hip_runtime.h>
#include <hip/hip_bf16.h>
#include <math.h>

#define D 128

typedef unsigned short ushort_t;
typedef __attribute__((ext_vector_type(8))) short bf16x8;
typedef __attribute__((ext_vector_type(4))) float f32x4;

// ---------- helpers ----------
__device__ __forceinline__ float bf2f(unsigned short u) {
    union { unsigned int i; float f; } c; c.i = ((unsigned int)u) << 16; return c.f;
}
__device__ __forceinline__ unsigned short f2bf(float f) {
    union { float f; unsigned int i; } c; c.f = f;
    unsigned int x = c.i + 0x7fffu + ((c.i >> 16) & 1u);   // RNE
    return (unsigned short)(x >> 16);
}
__device__ __forceinline__ float eluf(float x) { return x > 0.f ? x : (expf(x) - 1.f); }

// async global->LDS, 16B/lane; LDS dest = wave-uniform base + lane*16
__device__ __forceinline__ void gload_lds16(const void* g, void* l) {
    __builtin_amdgcn_global_load_lds(
        (const __attribute__((address_space(1))) unsigned int*)g,
        (__attribute__((address_space(3))) unsigned int*)l, 16, 0, 0);
}

// ---------- fused setup: [weight pack][x_item->bf16][degree histogram] ----------
// Bpack per source: [kc(4)][nt(8)][lane(64)][j(8)]; element = W[k][n],
// k=kc*32+(lane>>4)*8+j, n=nt*16+(lane&15)
// slots: 0:A'=W1t-W1b 1:W1b 2:it_Wl 3:it_Wr 4:st_Wl 5:st_Wr 6:sc_W2
__global__ __launch_bounds__(256) void k_setup(
    const float* __restrict__ sc_W1, const float* __restrict__ it_Wl,
    const float* __restrict__ it_Wr, const float* __restrict__ st_Wl,
    const float* __restrict__ st_Wr, const float* __restrict__ sc_W2,
    ushort_t* __restrict__ Bpack,
    const float* __restrict__ x_item, ushort_t* __restrict__ xi16, int nxi,
    const int* __restrict__ rdst, const int* __restrict__ rsrc,
    const int* __restrict__ pdst, int* __restrict__ counts,
    int e_r, int e_p, int n_item, int n_stu, int PACKB, int CVTB) {
    int bx = blockIdx.x, tid = threadIdx.x;
    if (bx < PACKB) {
        int t = bx * 256 + tid;
        int s = t >> 14;
        int r = t & 16383;
        int j = r & 7;
        int lane = (r >> 3) & 63;
        int tile = r >> 9;
        int nt = tile & 7, kc = tile >> 3;
        int n = nt * 16 + (lane & 15);
        int k = kc * 32 + ((lane >> 4) << 3) + j;
        float v;
        switch (s) {
            case 0: v = sc_W1[k * 128 + n] - sc_W1[(128 + k) * 128 + n]; break;
            case 1: v = sc_W1[(128 + k) * 128 + n]; break;
            case 2: v = it_Wl[k * 128 + n]; break;
            case 3: v = it_Wr[k * 128 + n]; break;
            case 4: v = st_Wl[k * 128 + n]; break;
            case 5: v = st_Wr[k * 128 + n]; break;
            default: v = sc_W2[k * 128 + n]; break;
        }
        Bpack[t] = f2bf(v);
    } else if (bx < PACKB + CVTB) {
        int base = (bx - PACKB) * 2048 + tid * 8;
        if (base < nxi) {
            const float* g = x_item + base;
            float4 a0 = ((const float4*)g)[0];
            float4 a1 = ((const float4*)g)[1];
            ushort4 u0 = { f2bf(a0.x), f2bf(a0.y), f2bf(a0.z), f2bf(a0.w) };
            ushort4 u1 = { f2bf(a1.x), f2bf(a1.y), f2bf(a1.z), f2bf(a1.w) };
            *(ushort4*)(xi16 + base)     = u0;
            *(ushort4*)(xi16 + base + 4) = u1;
        }
    } else {
        int i = (bx - PACKB - CVTB) * 256 + tid;
        int total = 2 * e_r + e_p;
        if (i >= total) return;
        if (i < e_r)            atomicAdd(&counts[rdst[i]], 1);
        else if (i < 2 * e_r)   atomicAdd(&counts[n_item + rsrc[i - e_r]], 1);
        else                    atomicAdd(&counts[n_item + n_stu + pdst[i - 2 * e_r]], 1);
    }
}

// ---------- scan phase A ----------
__global__ __launch_bounds__(256) void k_scanA(const int* __restrict__ counts,
                                               int* __restrict__ bsums, int NN) {
    __shared__ int red[256];
    int tid = threadIdx.x;
    int base = blockIdx.x * 1024 + tid * 4;
    int s = 0;
    #pragma unroll
    for (int j = 0; j < 4; ++j) { int idx = base + j; if (idx < NN) s += counts[idx]; }
    red[tid] = s; __syncthreads();
    for (int off = 128; off; off >>= 1) {
        if (tid < off) red[tid] += red[tid + off];
        __syncthreads();
    }
    if (tid == 0) bsums[blockIdx.x] = red[0];
}

// ---------- scan phase B ----------
__global__ __launch_bounds__(256) void k_scanB(int* __restrict__ bsums, int nb) {
    __shared__ int wsum[4];
    int tid = threadIdx.x;
    int lane = tid & 63, w = tid >> 6;
    int v = (tid < nb) ? bsums[tid] : 0;
    int orig = v;
    #pragma unroll
    for (int off = 1; off < 64; off <<= 1) {
        int t = __shfl_up(v, off, 64);
        if (lane >= off) v += t;
    }
    if (lane == 63) wsum[w] = v;
    __syncthreads();
    int wo = 0;
    #pragma unroll
    for (int i = 0; i < 4; ++i) if (i < w) wo += wsum[i];
    if (tid < nb) bsums[tid] = wo + v - orig;
}

// ---------- scan phase C: rowptr; cursor aliased into counts ----------
__global__ __launch_bounds__(256) void k_scanC(int* __restrict__ counts,
                                               const int* __restrict__ bsums,
                                               int* __restrict__ rowptr,
                                               int NN, int total) {
    __shared__ int wsum[4];
    int tid = threadIdx.x;
    int lane = tid & 63, w = tid >> 6;
    int base = blockIdx.x * 1024 + tid * 4;
    int c[4]; int ls = 0;
    #pragma unroll
    for (int j = 0; j < 4; ++j) { int idx = base + j; c[j] = (idx < NN) ? counts[idx] : 0; ls += c[j]; }
    int v = ls;
    #pragma unroll
    for (int off = 1; off < 64; off <<= 1) {
        int t = __shfl_up(v, off, 64);
        if (lane >= off) v += t;
    }
    if (lane == 63) wsum[w] = v;
    __syncthreads();
    int wo = 0;
    #pragma unroll
    for (int i = 0; i < 4; ++i) if (i < w) wo += wsum[i];
    int run = bsums[blockIdx.x] + wo + (v - ls);
    #pragma unroll
    for (int j = 0; j < 4; ++j) {
        int idx = base + j;
        if (idx < NN) {
            rowptr[idx] = run; counts[idx] = run;   // counts now = cursor
            if (idx == NN - 1) rowptr[NN] = total;
        }
        run += c[j];
    }
}

// ---------- scatter: payload = SOURCE node id (one less indirection in agg) ----------
__global__ __launch_bounds__(256) void k_scatter(const int* __restrict__ rdst,
                                                 const int* __restrict__ rsrc,
                                                 const int* __restrict__ pdst,
                                                 const int* __restrict__ psrc,
                                                 int* __restrict__ cursor,
                                                 int* __restrict__ payload,
                                                 int e_r, int e_p, int n_item, int n_stu) {
    int i = blockIdx.x * 256 + threadIdx.x;
    int total = 2 * e_r + e_p;
    if (i >= total) return;
    int g, src;
    if (i < e_r)          { g = rdst[i];                        src = rsrc[i]; }
    else if (i < 2 * e_r) { int j = i - e_r; g = n_item + rsrc[j]; src = rdst[j]; }
    else                  { int j = i - 2 * e_r; g = n_item + n_stu + pdst[j]; src = psrc[j]; }
    int slot = atomicAdd(&cursor[g], 1);
    payload[slot] = src;
}

// ---------- aggregation: 32-lane half-wave per node, bf16 gathers, unroll-4 ----------
__global__ __launch_bounds__(256) void k_agg(const ushort_t* __restrict__ xs16,
                                             const ushort_t* __restrict__ xi16,
                                             const ushort_t* __restrict__ U,
                                             const ushort_t* __restrict__ V,
                                             const int* __restrict__ rowptr,
                                             const int* __restrict__ payload,
                                             float* __restrict__ agg_item,
                                             float* __restrict__ agg_stu,
                                             ushort_t* __restrict__ hm16,
                                             int n_item, int n_stu) {
    int t = blockIdx.x * 256 + threadIdx.x;
    int node = t >> 5;
    int lane = t & 31;
    int NN = n_item + 2 * n_stu;
    if (node >= NN) return;
    int p0 = rowptr[node], p1 = rowptr[node + 1];
    float inv = 1.0f / (float)max(p1 - p0, 1);
    float ax = 0.f, ay = 0.f, az = 0.f, aw = 0.f;
    if (node < n_item + n_stu) {
        const ushort_t* src = (node < n_item) ? xs16 : xi16;
        int p = p0;
        for (; p + 4 <= p1; p += 4) {
            int e0 = payload[p], e1 = payload[p + 1], e2 = payload[p + 2], e3 = payload[p + 3];
            ushort4 r0 = *(const ushort4*)(src + (size_t)e0 * D + lane * 4);
            ushort4 r1 = *(const ushort4*)(src + (size_t)e1 * D + lane * 4);
            ushort4 r2 = *(const ushort4*)(src + (size_t)e2 * D + lane * 4);
            ushort4 r3 = *(const ushort4*)(src + (size_t)e3 * D + lane * 4);
            ax += (bf2f(r0.x) + bf2f(r1.x)) + (bf2f(r2.x) + bf2f(r3.x));
            ay += (bf2f(r0.y) + bf2f(r1.y)) + (bf2f(r2.y) + bf2f(r3.y));
            az += (bf2f(r0.z) + bf2f(r1.z)) + (bf2f(r2.z) + bf2f(r3.z));
            aw += (bf2f(r0.w) + bf2f(r1.w)) + (bf2f(r2.w) + bf2f(r3.w));
        }
        for (; p < p1; ++p) {
            int e = payload[p];
            ushort4 r = *(const ushort4*)(src + (size_t)e * D + lane * 4);
            ax += bf2f(r.x); ay += bf2f(r.y); az += bf2f(r.z); aw += bf2f(r.w);
        }
        float4 o = { ax * inv, ay * inv, az * inv, aw * inv };
        if (node < n_item) *(float4*)(agg_item + (size_t)node * D + lane * 4) = o;
        else               *(float4*)(agg_stu + (size_t)(node - n_item) * D + lane * 4) = o;
    } else {
        int n = node - n_item - n_stu;
        ushort4 vu = *(const ushort4*)(V + (size_t)n * D + lane * 4);
        float vx = bf2f(vu.x), vy = bf2f(vu.y), vz = bf2f(vu.z), vw = bf2f(vu.w);
        int p = p0;
        for (; p + 4 <= p1; p += 4) {
            int e0 = payload[p], e1 = payload[p + 1], e2 = payload[p + 2], e3 = payload[p + 3];
            ushort4 r0 = *(const ushort4*)(U + (size_t)e0 * D + lane * 4);
            ushort4 r1 = *(const ushort4*)(U + (size_t)e1 * D + lane * 4);
            ushort4 r2 = *(const ushort4*)(U + (size_t)e2 * D + lane * 4);
            ushort4 r3 = *(const ushort4*)(U + (size_t)e3 * D + lane * 4);
            ax += (eluf(bf2f(r0.x) + vx) + eluf(bf2f(r1.x) + vx)) + (eluf(bf2f(r2.x) + vx) + eluf(bf2f(r3.x) + vx));
            ay += (eluf(bf2f(r0.y) + vy) + eluf(bf2f(r1.y) + vy)) + (eluf(bf2f(r2.y) + vy) + eluf(bf2f(r3.y) + vy));
            az += (eluf(bf2f(r0.z) + vz) + eluf(bf2f(r1.z) + vz)) + (eluf(bf2f(r2.z) + vz) + eluf(bf2f(r3.z) + vz));
            aw += (eluf(bf2f(r0.w) + vw) + eluf(bf2f(r1.w) + vw)) + (eluf(bf2f(r2.w) + vw) + eluf(bf2f(r3.w) + vw));
        }
        for (; p < p1; ++p) {
            int e = payload[p];
            ushort4 r = *(const ushort4*)(U + (size_t)e * D + lane * 4);
            ax += eluf(bf2f(r.x) + vx); ay += eluf(bf2f(r.y) + vy);
            az += eluf(bf2f(r.z) + vz); aw += eluf(bf2f(r.w) + vw);
        }
        ushort4 o = { f2bf(ax * inv), f2bf(ay * inv), f2bf(az * inv), f2bf(aw * inv) };
        *(ushort4*)(hm16 + (size_t)n * D + lane * 4) = o;
    }
}

// ---------- MFMA GEMM core: acc += sum_s A_s[M,128] @ Bpack_s ----------
// 4 waves, 128x128 tile; A dtype per source: 0=fp32 (convert in staging,
// optional bf16 side-write), 1=bf16 (async global_load_lds, fragment-gather).
__device__ __forceinline__ void gemm_core(const void* A0, int t0,
                                          const void* A1, int t1,
                                          const void* A2, int t2,
                                          int nsrc, const ushort_t* Bp0,
                                          int M, int row0, ushort_t* xside,
                                          short* As, short* Bs, f32x4 (&acc)[4][4]) {
    const int tid = threadIdx.x;
    const int wave = tid >> 6, lane = tid & 63;
    const int mh = wave >> 1, nh = wave & 1;
    const int q = lane >> 4, l15 = lane & 15;
    #pragma unroll
    for (int i = 0; i < 4; ++i)
        #pragma unroll
        for (int j = 0; j < 4; ++j) acc[i][j] = (f32x4){0.f, 0.f, 0.f, 0.f};

    for (int s = 0; s < nsrc; ++s) {
        const void* Ap = (s == 0) ? A0 : ((s == 1) ? A1 : A2);
        const int at = (s == 0) ? t0 : ((s == 1) ? t1 : t2);
        const ushort_t* Bp = Bp0 + s * 16384;
        for (int h = 0; h < 2; ++h) {
            __syncthreads();
            #pragma unroll
            for (int it = 0; it < 4; ++it) {
                int tile = wave * 4 + it;
                int mt = tile & 7, kc = tile >> 3;
                int row = row0 + mt * 16 + l15;
                if (row >= M) row = M - 1;
                int k = h * 64 + kc * 32 + (q << 3);
                if (at == 0) {
                    const float* g = (const float*)Ap + (size_t)row * D + k;
                    float4 a0 = ((const float4*)g)[0];
                    float4 a1 = ((const float4*)g)[1];
                    ushort4 u0 = { f2bf(a0.x), f2bf(a0.y), f2bf(a0.z), f2bf(a0.w) };
                    ushort4 u1 = { f2bf(a1.x), f2bf(a1.y), f2bf(a1.z), f2bf(a1.w) };
                    short* dst = &As[tile * 512 + lane * 8];
                    *(ushort4*)dst       = u0;
                    *(ushort4*)(dst + 4) = u1;
                    if (xside) {
                        ushort_t* o = xside + (size_t)row * D + k;
                        *(ushort4*)o       = u0;
                        *(ushort4*)(o + 4) = u1;
                    }
                } else {
                    gload_lds16((const ushort_t*)Ap + (size_t)row * D + k, &As[tile * 512]);
                }
            }
            const ushort_t* bsrc = Bp + h * 8192;
            #pragma unroll
            for (int it = 0; it < 4; ++it) {
                int tile = wave * 4 + it;
                gload_lds16(bsrc + tile * 512 + lane * 8, &Bs[tile * 512]);
            }
            __syncthreads();
            #pragma unroll
            for (int kc = 0; kc < 2; ++kc) {
                bf16x8 a[4], b[4];
                #pragma unroll
                for (int i = 0; i < 4; ++i)
                    a[i] = *(bf16x8*)&As[(kc * 8 + mh * 4 + i) * 512 + lane * 8];
                #pragma unroll
                for (int j = 0; j < 4; ++j)
                    b[j] = *(bf16x8*)&Bs[(kc * 8 + nh * 4 + j) * 512 + lane * 8];
                #pragma unroll
                for (int i = 0; i < 4; ++i)
                    #pragma unroll
                    for (int j = 0; j < 4; ++j)
                        acc[i][j] = __builtin_amdgcn_mfma_f32_16x16x32_bf16(a[i], b[j], acc[i][j], 0, 0, 0);
            }
        }
    }
}

// ---------- U/V GEMM: gridDim.y selects {U = xs@A'+b1} or {V = xs@W1b}; y=0 side-writes xs16 ----------
__global__ __launch_bounds__(256) void k_gemmUV(const float* __restrict__ xs,
                                                const ushort_t* __restrict__ Bpack,
                                                const float* __restrict__ b1,
                                                ushort_t* __restrict__ U,
                                                ushort_t* __restrict__ V,
                                                ushort_t* __restrict__ xs16, int M) {
    __shared__ short As[8192];
    __shared__ short Bs[8192];
    const int y = blockIdx.y;
    f32x4 acc[4][4];
    gemm_core(xs, 0, nullptr, 0, nullptr, 0, 1, Bpack + y * 16384, M,
              blockIdx.x * 128, y == 0 ? xs16 : nullptr, As, Bs, acc);
    const int tid = threadIdx.x;
    const int wave = tid >> 6, lane = tid & 63;
    const int mh = wave >> 1, nh = wave & 1;
    const int q = lane >> 4, l15 = lane & 15;
    ushort_t* C = (y == 0) ? U : V;
    float bv[4];
    #pragma unroll
    for (int j = 0; j < 4; ++j) {
        int col = (nh * 4 + j) * 16 + l15;
        bv[j] = (y == 0) ? b1[col] : 0.f;
    }
    const int row0 = blockIdx.x * 128;
    #pragma unroll
    for (int i = 0; i < 4; ++i) {
        int rowbase = row0 + (mh * 4 + i) * 16 + (q << 2);
        #pragma unroll
        for (int r = 0; r < 4; ++r) {
            int row = rowbase + r;
            if (row >= M) continue;
            #pragma unroll
            for (int j = 0; j < 4; ++j) {
                int col = (nh * 4 + j) * 16 + l15;
                C[(size_t)row * D + col] = f2bf(acc[i][j][r] + bv[j]);
            }
        }
    }
}

// ---------- final GEMM, fused item+stu by block range, ELU + BN-stats in epilogue ----------
__global__ __launch_bounds__(256) void k_gemmF(const float* __restrict__ agg_item,
                                               const ushort_t* __restrict__ xi16,
                                               const float* __restrict__ agg_stu,
                                               const ushort_t* __restrict__ xs16,
                                               const ushort_t* __restrict__ hm16,
                                               const ushort_t* __restrict__ Bpack,
                                               const float* __restrict__ it_b,
                                               const float* __restrict__ st_b,
                                               const float* __restrict__ sc_b2,
                                               const int* __restrict__ rowptrS,
                                               float* __restrict__ out_item,
                                               float* __restrict__ out_stu,
                                               float* __restrict__ stats,
                                               int n_item, int n_stu, int gs_item) {
    __shared__ short As[8192];
    __shared__ short Bs[8192];
    const int bx = blockIdx.x;
    const bool is_item = bx < gs_item;
    f32x4 acc[4][4];
    int M, row0;
    const float* bias;
    float scale;
    float* C;
    float* st;
    if (is_item) {
        M = n_item; row0 = bx * 128;
        gemm_core(agg_item, 0, xi16, 1, nullptr, 1, 2, Bpack + 2 * 16384, M, row0,
                  nullptr, As, Bs, acc);
        bias = it_b; scale = 1.f; C = out_item; st = stats;
    } else {
        M = n_stu; row0 = (bx - gs_item) * 128;
        gemm_core(agg_stu, 0, xs16, 1, hm16, 1, 3, Bpack + 4 * 16384, M, row0,
                  nullptr, As, Bs, acc);
        bias = st_b; scale = 0.5f; C = out_stu; st = stats + 256;
    }
    const int tid = threadIdx.x;
    const int wave = tid >> 6, lane = tid & 63;
    const int mh = wave >> 1, nh = wave & 1;
    const int q = lane >> 4, l15 = lane & 15;
    float* sred = (float*)As;   // reuse LDS for 256-float column reduction
    __syncthreads();            // all As/Bs reads done
    sred[tid] = 0.f;
    __syncthreads();
    float bv[4], b2v[4];
    #pragma unroll
    for (int j = 0; j < 4; ++j) {
        int col = (nh * 4 + j) * 16 + l15;
        bv[j]  = bias[col];
        b2v[j] = is_item ? 0.f : sc_b2[col];
    }
    float ps[4] = {0.f, 0.f, 0.f, 0.f}, pq[4] = {0.f, 0.f, 0.f, 0.f};
    #pragma unroll
    for (int i = 0; i < 4; ++i) {
        int rowbase = row0 + (mh * 4 + i) * 16 + (q << 2);
        #pragma unroll
        for (int r = 0; r < 4; ++r) {
            int row = rowbase + r;
            if (row >= M) continue;
            float g = 0.f;
            if (!is_item) g = (rowptrS[row + 1] - rowptrS[row]) > 0 ? 1.f : 0.f;
            #pragma unroll
            for (int j = 0; j < 4; ++j) {
                int col = (nh * 4 + j) * 16 + l15;
                float v = acc[i][j][r] + bv[j];
                if (!is_item) v += g * b2v[j];
                v *= scale;
                v = eluf(v);
                C[(size_t)row * D + col] = v;
                ps[j] += v; pq[j] += v * v;
            }
        }
    }
    #pragma unroll
    for (int j = 0; j < 4; ++j) {
        int col = (nh * 4 + j) * 16 + l15;
        atomicAdd(&sred[col], ps[j]);
        atomicAdd(&sred[128 + col], pq[j]);
    }
    __syncthreads();
    atomicAdd(&st[tid], sred[tid]);
}

// ---------- BN apply, fused item+stu, float4 ----------
__global__ __launch_bounds__(256) void k_bnapply(float* __restrict__ out_item,
                                                 float* __restrict__ out_stu,
                                                 const float* __restrict__ stats,
                                                 const float* __restrict__ g_i,
                                                 const float* __restrict__ b_i,
                                                 const float* __restrict__ g_s,
                                                 const float* __restrict__ b_s,
                                                 int n_item, int n_stu, int blkItem) {
    int bx = blockIdx.x;
    float* X; const float* st; const float* gamma; const float* beta;
    float invM; int idx;
    if (bx < blkItem) {
        X = out_item; st = stats; gamma = g_i; beta = b_i;
        invM = 1.f / (float)n_item; idx = bx * 1024 + threadIdx.x * 4;
    } else {
        X = out_stu; st = stats + 256; gamma = g_s; beta = b_s;
        invM = 1.f / (float)n_stu; idx = (bx - blkItem) * 1024 + threadIdx.x * 4;
    }
    int c = idx & 127;
    float4 x = *(float4*)(X + idx);
    float o[4];
    #pragma unroll
    for (int j = 0; j < 4; ++j) {
        float mu = st[c + j] * invM;
        float var = st[128 + c + j] * invM - mu * mu;
        float v = (j == 0) ? x.x : (j == 1) ? x.y : (j == 2) ? x.z : x.w;
        o[j] = gamma[c + j] * (v - mu) * rsqrtf(var + 1e-5f) + beta[c + j];
    }
    float4 ov = { o[0], o[1], o[2], o[3] };
    *(float4*)(X + idx) = ov;
}

// ---------- host ----------
extern "C" void kernel_launch(void* const* d_in, const int* in_sizes, int n_in,
                              void* d_out, int out_size, void* d_ws, size_t ws_size,
                              hipStream_t stream) {
    const float* x_stu   = (const float*)d_in[0];
    const float* x_item  = (const float*)d_in[1];
    const int*   rsrc    = (const int*)d_in[2];
    const int*   rdst    = (const int*)d_in[3];
    const int*   psrc    = (const int*)d_in[4];
    const int*   pdst    = (const int*)d_in[5];
    const float* it_Wl   = (const float*)d_in[6];
    const float* it_Wr   = (const float*)d_in[7];
    const float* it_b    = (const float*)d_in[8];
    const float* st_Wl   = (const float*)d_in[9];
    const float* st_Wr   = (const float*)d_in[10];
    const float* st_b    = (const float*)d_in[11];
    const float* sc_W1   = (const float*)d_in[12];
    const float* sc_b1   = (const float*)d_in[13];
    const float* sc_W2   = (const float*)d_in[14];
    const float* sc_b2   = (const float*)d_in[15];
    const float* bn_it_g = (const float*)d_in[16];
    const float* bn_it_b = (const float*)d_in[17];
    const float* bn_st_g = (const float*)d_in[18];
    const float* bn_st_b = (const float*)d_in[19];

    const int n_stu  = in_sizes[0] / D;
    const int n_item = in_sizes[1] / D;
    const int e_r    = in_sizes[2];
    const int e_p    = in_sizes[4];
    const int NN     = n_item + 2 * n_stu;
    const int tot_e  = 2 * e_r + e_p;
    const int nb     = (NN + 1023) / 1024;

    // workspace layout (counts+stats adjacent for a single memset)
    char* w = (char*)d_ws;
    size_t off = 0;
    auto alloc = [&](size_t bytes) { char* p = w + off; off = (off + bytes + 255) & ~(size_t)255; return p; };
    int*      counts = (int*)alloc((size_t)NN * 4);            // -> cursor after scanC
    float*    stats  = (float*)alloc(512 * 4);
    int*      rowptr = (int*)alloc((size_t)(NN + 1) * 4);
    int*      bsums  = (int*)alloc(256 * 4);
    int*      payload= (int*)alloc((size_t)tot_e * 4);
    ushort_t* U      = (ushort_t*)alloc((size_t)n_stu * D * 2);
    ushort_t* V      = (ushort_t*)alloc((size_t)n_stu * D * 2);
    ushort_t* xs16   = (ushort_t*)alloc((size_t)n_stu * D * 2);
    ushort_t* xi16   = (ushort_t*)alloc((size_t)n_item * D * 2);
    ushort_t* hm16   = (ushort_t*)alloc((size_t)n_stu * D * 2);
    ushort_t* Bpack  = (ushort_t*)alloc(7 * 16384 * 2);
    (void)ws_size; (void)n_in; (void)out_size;

    // aggs staged fp32 in d_out (row-disjoint in-place for gemmF)
    float* out_item = (float*)d_out;
    float* out_stu  = (float*)d_out + (size_t)n_item * D;

    size_t zspan = (char*)(stats + 512) - (char*)counts;
    hipMemsetAsync(counts, 0, zspan, stream);

    const int PACKB = (7 * 16384) / 256;                 // 448
    const int nxi   = n_item * D;
    const int CVTB  = (nxi + 2047) / 2048;               // 1250
    const int HISTB = (tot_e + 255) / 256;               // 5079
    k_setup<<<PACKB + CVTB + HISTB, 256, 0, stream>>>(
        sc_W1, it_Wl, it_Wr, st_Wl, st_Wr, sc_W2, Bpack,
        x_item, xi16, nxi, rdst, rsrc, pdst, counts,
        e_r, e_p, n_item, n_stu, PACKB, CVTB);

    k_scanA<<<nb, 256, 0, stream>>>(counts, bsums, NN);
    k_scanB<<<1, 256, 0, stream>>>(bsums, nb);
    k_scanC<<<nb, 256, 0, stream>>>(counts, bsums, rowptr, NN, tot_e);
    k_scatter<<<HISTB, 256, 0, stream>>>(rdst, rsrc, pdst, psrc, counts, payload,
                                         e_r, e_p, n_item, n_stu);

    const int gs_stu  = (n_stu + 127) / 128;
    const int gs_item = (n_item + 127) / 128;

    k_gemmUV<<<dim3(gs_stu, 2), 256, 0, stream>>>(x_stu, Bpack, sc_b1, U, V, xs16, n_stu);

    k_agg<<<((size_t)NN * 32 + 255) / 256, 256, 0, stream>>>(
        xs16, xi16, U, V, rowptr, payload, out_item, out_stu, hm16, n_item, n_stu);

    k_gemmF<<<gs_item + gs_stu, 256, 0, stream>>>(
        out_item, xi16, out_stu, xs16, hm16, Bpack, it_b, st_b, sc_b2,
        rowptr + n_item + n_stu, out_item, out_stu, stats, n_item, n_stu, gs_item);

    const int blkItem = (n_item * D) / 1024;             // 2500
    const int blkStu  = (n_stu * D) / 1024;              // 12500
    k_bnapply<<<blkItem + blkStu, 256, 0, stream>>>(
        out_item, out_stu, stats, bn_it_g, bn_it_b, bn_st_g, bn_st_b,
        n_item, n_stu, blkItem);
}